// Round 1
// 546.926 us; speedup vs baseline: 1.0636x; 1.0636x over previous
//
#include <hip/hip_runtime.h>
#include <cmath>

// Problem constants (B_SZ=2, L=2048, D=1024, N=16)
#define D_DIM 1024
#define N_DIM 16
#define KTOT  2049          // 2*D + 1 (concat axis)
#define WS_STRIDE 36        // per-(b,l) row in ws: B[16], C[16 unused], sd @32

typedef float v4f __attribute__((ext_vector_type(4)));

// ---------------------------------------------------------------------------
// Kernel 1: projections. One block (256 thr = 4 waves) per (b,l) token.
//   wave 0: B rows 0..7  (+ s_delta)      -> ws
//   wave 1: B rows 8..15                  -> ws
//   wave 2: C rows 0..7                   -> out[.., k=2048, 0..7]
//   wave 3: C rows 8..15                  -> out[.., k=2048, 8..15]
// ---------------------------------------------------------------------------
__global__ __launch_bounds__(256) void proj_kernel(
    const float* __restrict__ x, const float* __restrict__ W_b,
    const float* __restrict__ W_c, const float* __restrict__ W_delta,
    float* __restrict__ ws, float* __restrict__ out)
{
    const int bl   = blockIdx.x;
    const int tid  = threadIdx.x;
    const int wave = tid >> 6;
    const int lane = tid & 63;

    const float* xrow  = x + (size_t)bl * D_DIM;
    const float* Wbase = (wave < 2) ? W_b : W_c;
    const int rowbase  = (wave & 1) * 8;

    float acc[8] = {0.f,0.f,0.f,0.f,0.f,0.f,0.f,0.f};
    float sd = 0.f;

    for (int i = 0; i < D_DIM / 64; ++i) {
        const int d = lane + (i << 6);
        const float xv = xrow[d];
        #pragma unroll
        for (int r = 0; r < 8; ++r)
            acc[r] = fmaf(xv, Wbase[(rowbase + r) * D_DIM + d], acc[r]);
        if (wave == 0) sd = fmaf(xv, W_delta[d], sd);
    }

    // full 64-lane xor-shuffle reduction
    #pragma unroll
    for (int r = 0; r < 8; ++r) {
        #pragma unroll
        for (int m = 32; m >= 1; m >>= 1)
            acc[r] += __shfl_xor(acc[r], m, 64);
    }
    if (wave == 0) {
        #pragma unroll
        for (int m = 32; m >= 1; m >>= 1)
            sd += __shfl_xor(sd, m, 64);
    }

    if (lane == 0) {
        if (wave < 2) {
            float* dst = ws + (size_t)bl * WS_STRIDE + rowbase;
            #pragma unroll
            for (int r = 0; r < 8; ++r) dst[r] = acc[r];
            if (wave == 0) ws[(size_t)bl * WS_STRIDE + 32] = sd;
        } else {
            // C goes straight into the k = 2*D slot of the output
            float* dst = out + ((size_t)bl * KTOT + 2 * D_DIM) * N_DIM + rowbase;
            #pragma unroll
            for (int r = 0; r < 8; ++r) dst[r] = acc[r];
        }
    }
}

// ---------------------------------------------------------------------------
// Kernel 2: the 537 MB elementwise expansion. 16 blocks per (b,l);
// thread = (dloc = tid>>2 in 0..63, n4 = tid&3). Each thread writes two
// nontemporal float4s: A_bar at k=d, deltaB_x at k=D+d. Block writes two
// contiguous 4 KB chunks -> fully coalesced streaming stores.
//
// Math is all native-rate and branchless now (prev version was VALU-throttled
// by libm expm1f/log1pf divergence + 4 IEEE divides per thread):
//  - softplus via v_exp_f32/v_log_f32 (arg of log in (1,2], no edge cases)
//  - A_bar = __expf(dA)  (matches the reference's exp(dA) to ~2 ulp)
//  - ratio = (A_bar-1)/dA:
//      |dA| >= 0.5 : (A_bar-1) * v_rcp_f32(dA)   -- same cancellation the
//                    fp32 REFERENCE has, so it tracks the ref closely
//      |dA| <  0.5 : 6-term Taylor of (e^u-1)/u  -- exact where cancellation
//                    would hurt; no divide, no branch (v_cndmask select)
// ---------------------------------------------------------------------------
__global__ __launch_bounds__(256) void ssm_kernel(
    const float* __restrict__ x, const float* __restrict__ A,
    const float* __restrict__ delta_param, const float* __restrict__ ws,
    float* __restrict__ out)
{
    const int blk   = blockIdx.x;
    const int bl    = blk >> 4;
    const int chunk = blk & 15;
    const int tid   = threadIdx.x;
    const int n4    = tid & 3;
    const int dloc  = tid >> 2;
    const int d     = (chunk << 6) + dloc;

    const float sd = ws[bl * WS_STRIDE + 32];
    const v4f   Bv = *(const v4f*)(ws + bl * WS_STRIDE + (n4 << 2));
    const float dp = delta_param[d];
    const v4f   Av = *(const v4f*)(A + (size_t)d * N_DIM + (n4 << 2));
    const float xv = x[(size_t)bl * D_DIM + d];

    // Delta = softplus(sd + delta_param[d]) = max(z,0) + log(1 + exp(-|z|))
    // exp arg <= 0 -> e in (0,1]; log arg in (1,2] -> native ops are safe.
    const float z     = sd + dp;
    const float e     = __expf(-fabsf(z));            // v_exp_f32
    const float Delta = fmaxf(z, 0.0f) + __logf(1.0f + e);  // v_log_f32
    const float dx    = Delta * xv;

    v4f Abar, dbx;
    #pragma unroll
    for (int i = 0; i < 4; ++i) {
        const float dA = Delta * Av[i];
        const float ab = __expf(dA);                  // A_bar = exp(dA)
        const float em = ab - 1.0f;
        const float r_big = em * __builtin_amdgcn_rcpf(dA);   // v_rcp_f32
        // (e^u - 1)/u = 1 + u/2 + u^2/6 + u^3/24 + u^4/120 + u^5/720
        const float r_small =
            fmaf(dA, fmaf(dA, fmaf(dA, fmaf(dA, fmaf(dA,
                1.3888889e-3f,   // 1/720
                8.3333333e-3f),  // 1/120
                4.1666667e-2f),  // 1/24
                1.6666667e-1f),  // 1/6
                0.5f), 1.0f);
        const float ratio = (fabsf(dA) < 0.5f) ? r_small : r_big;
        Abar[i] = ab;
        dbx[i]  = ratio * Bv[i] * dx;   // (A_bar-1)/dA * Delta*B * x
    }

    const size_t base = ((size_t)bl * KTOT + d) * N_DIM + (n4 << 2);
    __builtin_nontemporal_store(Abar, (v4f*)(out + base));
    __builtin_nontemporal_store(dbx,  (v4f*)(out + base + (size_t)D_DIM * N_DIM));
}

extern "C" void kernel_launch(void* const* d_in, const int* in_sizes, int n_in,
                              void* d_out, int out_size, void* d_ws, size_t ws_size,
                              hipStream_t stream)
{
    const float* x           = (const float*)d_in[0];
    const float* W_b         = (const float*)d_in[1];
    const float* W_c         = (const float*)d_in[2];
    const float* W_delta     = (const float*)d_in[3];
    const float* A           = (const float*)d_in[4];
    const float* delta_param = (const float*)d_in[5];
    float* out = (float*)d_out;
    float* ws  = (float*)d_ws;

    const int BL = in_sizes[0] / D_DIM;   // 4096 tokens

    proj_kernel<<<BL, 256, 0, stream>>>(x, W_b, W_c, W_delta, ws, out);
    ssm_kernel<<<BL * 16, 256, 0, stream>>>(x, A, delta_param, ws, out);
}